// Round 4
// baseline (536.299 us; speedup 1.0000x reference)
//
#include <hip/hip_runtime.h>
#include <hip/hip_bf16.h>
#include <hip/hip_fp16.h>

// ---------------- workspace layout (u32 words) ----------------
// g     [256]  f32 (atomic accum, memset 0)
// scal  [2]    f32 (ssq, sasn)  (atomic accum, memset 0)
// ninfo [N*8]  f32 {xs0..xs4, cnt, deg, dis}   (plain stores from k_scan)
// keys  [E]    u32 (src<<16 | dst)   -- requires N <= 65536 (N=50000)
// Sh    [N*128] u32 = 256 halves/node (S row, permuted layout)
// pooled[32768] f32
// parts [nparts*16384] (32768 bf16 per part)

typedef _Float16 half2v __attribute__((ext_vector_type(2)));

__device__ inline float fdot2u(uint32_t a, uint32_t b, float c) {
#if __has_builtin(__builtin_amdgcn_fdot2)
    return __builtin_amdgcn_fdot2(__builtin_bit_cast(half2v, a),
                                  __builtin_bit_cast(half2v, b), c, false);
#else
    __half2 ha = *reinterpret_cast<__half2*>(&a);
    __half2 hb = *reinterpret_cast<__half2*>(&b);
    float2 fa = __half22float2(ha), fb = __half22float2(hb);
    return c + fa.x * fb.x + fa.y * fb.y;
#endif
}

__device__ inline uint32_t pack_h2(float a, float b) {
    __half2 h = __floats2half2_rn(a, b);
    return *reinterpret_cast<uint32_t*>(&h);
}

// ---------------- Kernel P: pack edge index rows into u32 keys ----
__global__ void k_pack(const int* __restrict__ ei, uint32_t* __restrict__ keys, int E) {
    int e = blockIdx.x * blockDim.x + threadIdx.x;
    if (e < E)
        keys[e] = ((uint32_t)ei[e] << 16) | (uint32_t)ei[E + e];
}

// ---------------- Kernel A: range-owned edge aggregation ----------
// Block b exclusively owns nodes [b*256, b*256+256). It scans ALL edge keys,
// accumulates dst-matched {x[src], cnt} and src-matched {deg} into LDS f32,
// then flushes with plain stores. No global atomics.
#define PR 256
__launch_bounds__(1024)
__global__ void k_scan(const uint32_t* __restrict__ keys, const float* __restrict__ ew,
                       const float* __restrict__ x, float* __restrict__ ninfo,
                       int N, int E) {
    __shared__ float accx[PR][6];   // xs0..xs4, cnt
    __shared__ float accd[PR];      // deg
    int t = threadIdx.x;
    uint32_t base = blockIdx.x * PR;
    uint32_t pr = (uint32_t)min(PR, N - (int)base);

    for (int k = t; k < PR * 6; k += 1024) (&accx[0][0])[k] = 0.f;
    for (int k = t; k < PR; k += 1024) accd[k] = 0.f;
    __syncthreads();

    int nvec = E >> 2;
    const uint4* kv = (const uint4*)keys;
    for (int i = t; i < nvec; i += 1024) {
        uint4 kk = kv[i];
        int e0 = i << 2;
        #pragma unroll
        for (int j = 0; j < 4; j++) {
            uint32_t k = (&kk.x)[j];
            uint32_t dst = k & 0xffffu;
            uint32_t src = k >> 16;
            uint32_t ud = dst - base;
            if (ud < pr) {
                const float* xp = x + (size_t)src * 5;
                atomicAdd(&accx[ud][0], xp[0]);
                atomicAdd(&accx[ud][1], xp[1]);
                atomicAdd(&accx[ud][2], xp[2]);
                atomicAdd(&accx[ud][3], xp[3]);
                atomicAdd(&accx[ud][4], xp[4]);
                atomicAdd(&accx[ud][5], 1.0f);
            }
            uint32_t us = src - base;
            if (us < pr) {
                atomicAdd(&accd[us], ew[e0 + j]);
            }
        }
    }
    for (int e = (nvec << 2) + t; e < E; e += 1024) {
        uint32_t k = keys[e];
        uint32_t dst = k & 0xffffu;
        uint32_t src = k >> 16;
        uint32_t ud = dst - base;
        if (ud < pr) {
            const float* xp = x + (size_t)src * 5;
            atomicAdd(&accx[ud][0], xp[0]);
            atomicAdd(&accx[ud][1], xp[1]);
            atomicAdd(&accx[ud][2], xp[2]);
            atomicAdd(&accx[ud][3], xp[3]);
            atomicAdd(&accx[ud][4], xp[4]);
            atomicAdd(&accx[ud][5], 1.0f);
        }
        uint32_t us = src - base;
        if (us < pr) atomicAdd(&accd[us], ew[e]);
    }
    __syncthreads();

    for (uint32_t n = t; n < pr; n += 1024) {
        float dg = accd[n];
        float dis = (dg > 0.f) ? rsqrtf(fmaxf(dg, 1e-30f)) : 0.f;
        float* o = ninfo + (size_t)(base + n) * 8;
        float4 lo = make_float4(accx[n][0], accx[n][1], accx[n][2], accx[n][3]);
        float4 hi = make_float4(accx[n][4], accx[n][5], dg, dis);
        *(float4*)(o + 0) = lo;
        *(float4*)(o + 4) = hi;
    }
}

// ---------------- Kernel B: fused node phase ----------------------
// tile = 32 nodes; node phase: 32 threads/node (sub = t&31, cols sub+32j);
// GEMM phase: wave owns 16 clusters (broadcast S), lane owns 2 features.
__launch_bounds__(1024)
__global__ void k_node(const float* __restrict__ x,
                       const float* __restrict__ ninfo,
                       const float* __restrict__ W1p, const float* __restrict__ R1p,
                       const float* __restrict__ b1p,
                       const float* __restrict__ W1e, const float* __restrict__ R1e,
                       const float* __restrict__ b1e,
                       uint32_t* __restrict__ Sh,
                       __hip_bfloat16* __restrict__ parts,
                       float* __restrict__ scal, int N) {
    __shared__ float S_t[32][256];
    __shared__ float Y_t[32][128];
    __shared__ float red[16];

    int t = threadIdx.x;
    int wv = t >> 6, l = t & 63;
    int nl = t >> 5, sub = t & 31;

    float acc[16][2];
    #pragma unroll
    for (int ci = 0; ci < 16; ci++) { acc[ci][0] = 0.f; acc[ci][1] = 0.f; }
    float ssq = 0.f;

    int ntiles = (N + 31) >> 5;
    for (int tile = blockIdx.x; tile < ntiles; tile += (int)gridDim.x) {
        int i = tile * 32 + nl;
        if (i < N) {
            const float4* ni = (const float4*)(ninfo + (size_t)i * 8);
            float4 plo = ni[0];
            float4 phi = ni[1];
            float dg = phi.z;
            float inv_dn = 1.0f / fmaxf(phi.y, 1.0f);
            float z[10];
            z[0] = plo.x * inv_dn; z[1] = plo.y * inv_dn; z[2] = plo.z * inv_dn;
            z[3] = plo.w * inv_dn; z[4] = phi.x * inv_dn;
            const float* xp = x + (size_t)i * 5;
            z[5] = xp[0]; z[6] = xp[1]; z[7] = xp[2]; z[8] = xp[3]; z[9] = xp[4];
            // mat_s: 8 cols, c = sub + 32*j (conflict-free, coalesced, L1-hot weights)
            float m[8];
            #pragma unroll
            for (int j = 0; j < 8; j++) {
                int c = sub + 32 * j;
                float v = b1p[c];
                #pragma unroll
                for (int d = 0; d < 5; d++) v += z[d] * W1p[d * 256 + c];
                #pragma unroll
                for (int d = 0; d < 5; d++) v += z[5 + d] * R1p[d * 256 + c];
                m[j] = v;
            }
            float mx = m[0];
            #pragma unroll
            for (int j = 1; j < 8; j++) mx = fmaxf(mx, m[j]);
            #pragma unroll
            for (int o = 16; o > 0; o >>= 1) mx = fmaxf(mx, __shfl_xor(mx, o));
            float ls = 0.f;
            #pragma unroll
            for (int j = 0; j < 8; j++) { m[j] = __expf(m[j] - mx); ls += m[j]; }
            #pragma unroll
            for (int o = 16; o > 0; o >>= 1) ls += __shfl_xor(ls, o);
            float inv_l = 1.0f / ls;
            float sq = 0.f;
            #pragma unroll
            for (int j = 0; j < 8; j++) {
                float s = m[j] * inv_l;
                m[j] = s;
                S_t[nl][sub + 32 * j] = s;
                sq += s * s;
            }
            if (dg > 0.f) ssq += sq;
            // store S row as halves (permuted layout: pos = sub*8 + j; dot is
            // permutation-invariant so both edge endpoints match)
            uint4 sp;
            sp.x = pack_h2(m[0], m[1]);
            sp.y = pack_h2(m[2], m[3]);
            sp.z = pack_h2(m[4], m[5]);
            sp.w = pack_h2(m[6], m[7]);
            *(uint4*)&Sh[(size_t)i * 128 + sub * 4] = sp;
            // mat_y: 4 cols, f = sub + 32*j
            #pragma unroll
            for (int j = 0; j < 4; j++) {
                int f = sub + 32 * j;
                float v = b1e[f];
                #pragma unroll
                for (int d = 0; d < 5; d++) v += z[d] * W1e[d * 128 + f];
                #pragma unroll
                for (int d = 0; d < 5; d++) v += z[5 + d] * R1e[d * 128 + f];
                Y_t[nl][f] = fmaxf(v, 0.f);
            }
        } else {
            #pragma unroll
            for (int j = 0; j < 8; j++) S_t[nl][sub + 32 * j] = 0.f;
            #pragma unroll
            for (int j = 0; j < 4; j++) Y_t[nl][sub + 32 * j] = 0.f;
        }
        __syncthreads();
        // mini-GEMM: acc[ci][f] += S_t[k][wv*16+ci] * Y_t[k][l*2+f]
        #pragma unroll 4
        for (int k = 0; k < 32; k++) {
            float4 s0 = *(const float4*)&S_t[k][wv * 16 + 0];
            float4 s1 = *(const float4*)&S_t[k][wv * 16 + 4];
            float4 s2 = *(const float4*)&S_t[k][wv * 16 + 8];
            float4 s3 = *(const float4*)&S_t[k][wv * 16 + 12];
            float2 y  = *(const float2*)&Y_t[k][l * 2];
            float sv[16] = {s0.x, s0.y, s0.z, s0.w, s1.x, s1.y, s1.z, s1.w,
                            s2.x, s2.y, s2.z, s2.w, s3.x, s3.y, s3.z, s3.w};
            #pragma unroll
            for (int ci = 0; ci < 16; ci++) {
                acc[ci][0] += sv[ci] * y.x;
                acc[ci][1] += sv[ci] * y.y;
            }
        }
        __syncthreads();
    }

    // coalesced bf16 partial store: part[(wv*16+ci)*128 + l*2 + f]
    __hip_bfloat16* part = parts + (size_t)blockIdx.x * 32768;
    #pragma unroll
    for (int ci = 0; ci < 16; ci++) {
        __hip_bfloat162 pr;
        pr.x = __float2bfloat16(acc[ci][0]);
        pr.y = __float2bfloat16(acc[ci][1]);
        *(__hip_bfloat162*)&part[(size_t)(wv * 16 + ci) * 128 + l * 2] = pr;
    }

    #pragma unroll
    for (int o = 32; o > 0; o >>= 1) ssq += __shfl_xor(ssq, o);
    if (l == 0) red[wv] = ssq;
    __syncthreads();
    if (t == 0) {
        float s = 0.f;
        #pragma unroll
        for (int w2 = 0; w2 < 16; w2++) s += red[w2];
        atomicAdd(&scal[0], s);
    }
}

// ---------------- Kernel B2: reduce partials ----------------------
__global__ void k_reduce(const __hip_bfloat16* __restrict__ parts,
                         float* __restrict__ pooled, int nparts) {
    int idx = blockIdx.x * blockDim.x + threadIdx.x;  // 32768 total
    float s = 0.f;
    for (int p = 0; p < nparts; p++)
        s += __bfloat162float(parts[(size_t)p * 32768 + idx]);
    pooled[idx] = s;
}

// ---------------- Kernel C: per-edge regularizer ------------------
// sasn = sum_e w_e * dis[s] * dis[d] * <S_s, S_d>, S rows stored as f16.
// 16 lanes per edge: lane sub reads 16B chunk sub of each row; fdot2; reduce.
__launch_bounds__(256)
__global__ void k_edge_reg(const uint32_t* __restrict__ keys, const float* __restrict__ ew,
                           const uint32_t* __restrict__ Sh, const float* __restrict__ ninfo,
                           float* __restrict__ scal, int E) {
    __shared__ float red[4];
    int t = threadIdx.x;
    int lane = t & 63;
    int sub = lane & 15;
    int grp = lane >> 4;
    int wv = t >> 6;
    int gw = blockIdx.x * (blockDim.x >> 6) + wv;
    int nwaves = gridDim.x * (blockDim.x >> 6);

    float acc = 0.f;
    for (int base = gw * 4; base < E; base += nwaves * 4) {
        int e = base + grp;
        float dot = 0.f;
        float sc = 0.f;
        if (e < E) {
            uint32_t k = keys[e];
            int s = (int)(k >> 16);
            int d = (int)(k & 0xffffu);
            const uint4* pa = (const uint4*)(Sh + (size_t)s * 128) + sub;
            const uint4* pb = (const uint4*)(Sh + (size_t)d * 128) + sub;
            uint4 A = *pa;
            uint4 B = *pb;
            dot = fdot2u(A.x, B.x, dot);
            dot = fdot2u(A.y, B.y, dot);
            dot = fdot2u(A.z, B.z, dot);
            dot = fdot2u(A.w, B.w, dot);
            sc = ew[e] * ninfo[(size_t)s * 8 + 7] * ninfo[(size_t)d * 8 + 7];
        }
        #pragma unroll
        for (int o = 8; o > 0; o >>= 1) dot += __shfl_xor(dot, o);
        if (sub == 0) acc += sc * dot;
    }

    #pragma unroll
    for (int o = 32; o > 0; o >>= 1) acc += __shfl_xor(acc, o);
    if (lane == 0) red[wv] = acc;
    __syncthreads();
    if (t == 0) atomicAdd(&scal[1], red[0] + red[1] + red[2] + red[3]);
}

// ---------------- Kernel D1: y2 column sums -----------------------
__launch_bounds__(256)
__global__ void k_pool2(const float* __restrict__ pooled,
                        const float* __restrict__ W2e, const float* __restrict__ R2e,
                        const float* __restrict__ b2e, float* __restrict__ g) {
    __shared__ float mh[128];
    __shared__ float prow[128];
    int t = threadIdx.x;
    int c = blockIdx.x;
    if (t < 128) {
        float s = 0.f;
        for (int cc = 0; cc < 256; cc++) s += pooled[cc * 128 + t];
        mh[t] = s * (1.0f / 256.0f);
        prow[t] = pooled[c * 128 + t];
    }
    __syncthreads();
    float v = b2e[t];
    for (int k = 0; k < 128; k++)
        v += mh[k] * W2e[k * 256 + t] + prow[k] * R2e[k * 256 + t];
    v = fmaxf(v, 0.f);
    atomicAdd(&g[t], v);
}

// ---------------- Kernel D2: final MLP + output -------------------
__launch_bounds__(256)
__global__ void k_final(const float* __restrict__ g,
                        const float* __restrict__ Wl1, const float* __restrict__ bl1,
                        const float* __restrict__ Wl2, const float* __restrict__ bl2,
                        const float* __restrict__ scal, float* __restrict__ out, int N) {
    __shared__ float gs[256];
    __shared__ float h1[256];
    __shared__ float lg[10];
    int t = threadIdx.x;
    gs[t] = g[t];
    __syncthreads();
    float v = bl1[t];
    for (int k = 0; k < 256; k++) v += gs[k] * Wl1[k * 256 + t];
    h1[t] = fmaxf(v, 0.f);
    __syncthreads();
    if (t < 10) {
        float s = bl2[t];
        for (int k = 0; k < 256; k++) s += h1[k] * Wl2[k * 10 + t];
        lg[t] = s;
    }
    __syncthreads();
    if (t == 0) {
        float mx = lg[0];
        for (int j = 1; j < 10; j++) mx = fmaxf(mx, lg[j]);
        float ls = 0.f;
        for (int j = 0; j < 10; j++) ls += __expf(lg[j] - mx);
        float lse = mx + logf(ls);
        for (int j = 0; j < 10; j++) out[j] = lg[j] - lse;
        out[10] = (scal[0] - scal[1]) / (float)N;
    }
}

extern "C" void kernel_launch(void* const* d_in, const int* in_sizes, int n_in,
                              void* d_out, int out_size, void* d_ws, size_t ws_size,
                              hipStream_t stream) {
    const float* x   = (const float*)d_in[0];
    const int*   ei  = (const int*)d_in[1];
    const float* ew  = (const float*)d_in[2];
    const float* W1p = (const float*)d_in[3];
    const float* R1p = (const float*)d_in[4];
    const float* b1p = (const float*)d_in[5];
    const float* W1e = (const float*)d_in[6];
    const float* R1e = (const float*)d_in[7];
    const float* b1e = (const float*)d_in[8];
    // d_in[9..11] = W2p,R2p,b2p : dead (softmax over size-1 axis == 1)
    const float* W2e = (const float*)d_in[12];
    const float* R2e = (const float*)d_in[13];
    const float* b2e = (const float*)d_in[14];
    const float* Wl1 = (const float*)d_in[15];
    const float* bl1 = (const float*)d_in[16];
    const float* Wl2 = (const float*)d_in[17];
    const float* bl2 = (const float*)d_in[18];
    float* out = (float*)d_out;

    int N = in_sizes[0] / 5;
    int E = in_sizes[1] / 2;

    uint32_t* ws = (uint32_t*)d_ws;
    size_t off = 0;
    float* g    = (float*)(ws + off); off += 256;
    float* scal = (float*)(ws + off); off += 2;
    size_t zero_words = off;                       // accumulators to clear
    off = (off + 3) & ~(size_t)3;                  // 16B align
    float* ninfo = (float*)(ws + off); off += (size_t)N * 8;
    uint32_t* keys = ws + off; off += (size_t)E;
    off = (off + 3) & ~(size_t)3;
    uint32_t* Sh = ws + off; off += (size_t)N * 128;
    float* pooled = (float*)(ws + off); off += 32768;
    size_t avail = (ws_size / 4 > off) ? (ws_size / 4 - off) : 0;
    int nparts = (int)(avail / 16384);
    if (nparts > 256) nparts = 256;
    if (nparts < 1) nparts = 1;
    __hip_bfloat16* parts = (__hip_bfloat16*)(ws + off);

    hipMemsetAsync(d_ws, 0, zero_words * 4, stream);

    k_pack<<<(E + 255) / 256, 256, 0, stream>>>(ei, keys, E);
    k_scan<<<(N + PR - 1) / PR, 1024, 0, stream>>>(keys, ew, x, ninfo, N, E);
    k_node<<<nparts, 1024, 0, stream>>>(x, ninfo, W1p, R1p, b1p,
                                        W1e, R1e, b1e, Sh, parts, scal, N);
    k_reduce<<<128, 256, 0, stream>>>(parts, pooled, nparts);
    k_edge_reg<<<2048, 256, 0, stream>>>(keys, ew, Sh, ninfo, scal, E);
    k_pool2<<<256, 256, 0, stream>>>(pooled, W2e, R2e, b2e, g);
    k_final<<<1, 256, 0, stream>>>(g, Wl1, bl1, Wl2, bl2, scal, out, N);
}

// Round 5
// 439.094 us; speedup vs baseline: 1.2214x; 1.2214x over previous
//
#include <hip/hip_runtime.h>
#include <hip/hip_bf16.h>
#include <hip/hip_fp16.h>

// ---------------- workspace layout (u32 words) ----------------
// g     [256]   f32 (atomic accum, memset 0)
// scal  [2]     f32 (ssq, sasn) (atomic accum, memset 0)
// hd    [256]   int dst-bucket histogram (memset 0)
// hs    [256]   int src-bucket histogram (memset 0)
// offd  [257], offs [257], cd [256], cs [256]  (written by k_prefix)
// ninfo [N*8]   f32 {xs0..xs4, cnt, deg, dis}
// keys  [E]     u32 (src<<16 | dst)  -- requires N <= 65536 (N=50000)
// bd    [E]     u32 dst-binned keys
// bs    [E]     u32 src-binned {h16(ew)<<16 | src&0xff}
// Sh    [N*128] u32 = 256 halves/node (S row, permuted layout)
// pooled[32768] f32
// parts [nparts*16384] (32768 bf16 per part)

#define PR 256
#define NBMAX 256
#define SCH 2048

typedef _Float16 half2v __attribute__((ext_vector_type(2)));

__device__ inline float fdot2u(uint32_t a, uint32_t b, float c) {
#if __has_builtin(__builtin_amdgcn_fdot2)
    return __builtin_amdgcn_fdot2(__builtin_bit_cast(half2v, a),
                                  __builtin_bit_cast(half2v, b), c, false);
#else
    __half2 ha = *reinterpret_cast<__half2*>(&a);
    __half2 hb = *reinterpret_cast<__half2*>(&b);
    float2 fa = __half22float2(ha), fb = __half22float2(hb);
    return c + fa.x * fb.x + fa.y * fb.y;
#endif
}

__device__ inline uint32_t pack_h2(float a, float b) {
    __half2 h = __floats2half2_rn(a, b);
    return *reinterpret_cast<uint32_t*>(&h);
}

// ---------------- Kernel H: pack keys + global bucket histogram ---
__launch_bounds__(1024)
__global__ void k_hist(const int* __restrict__ ei, uint32_t* __restrict__ keys,
                       int* __restrict__ hd, int* __restrict__ hs, int E) {
    __shared__ int lhd[NBMAX], lhs[NBMAX];
    int t = threadIdx.x;
    if (t < NBMAX) { lhd[t] = 0; lhs[t] = 0; }
    __syncthreads();
    int idx = blockIdx.x * blockDim.x + t;
    int stride = gridDim.x * blockDim.x;
    for (int e = idx; e < E; e += stride) {
        uint32_t s = (uint32_t)ei[e];
        uint32_t d = (uint32_t)ei[E + e];
        keys[e] = (s << 16) | d;
        atomicAdd(&lhd[d >> 8], 1);
        atomicAdd(&lhs[s >> 8], 1);
    }
    __syncthreads();
    if (t < NBMAX) {
        if (lhd[t]) atomicAdd(&hd[t], lhd[t]);
        if (lhs[t]) atomicAdd(&hs[t], lhs[t]);
    }
}

// ---------------- Kernel X: exclusive prefix + init cursors -------
__global__ void k_prefix(const int* __restrict__ hd, const int* __restrict__ hs,
                         int* __restrict__ offd, int* __restrict__ offs,
                         int* __restrict__ cd, int* __restrict__ cs, int NB) {
    if (threadIdx.x == 0 && blockIdx.x == 0) {
        int a = 0;
        for (int i = 0; i < NB; i++) { offd[i] = a; cd[i] = a; a += hd[i]; }
        offd[NB] = a;
        int b = 0;
        for (int i = 0; i < NB; i++) { offs[i] = b; cs[i] = b; b += hs[i]; }
        offs[NB] = b;
    }
}

// ---------------- Kernel S: block counting-sort scatter -----------
__launch_bounds__(1024)
__global__ void k_scatter(const uint32_t* __restrict__ keys, const float* __restrict__ ew,
                          int* __restrict__ cd, int* __restrict__ cs,
                          uint32_t* __restrict__ bd, uint32_t* __restrict__ bs,
                          int E, int NB) {
    __shared__ int lhd[NBMAX], lhs[NBMAX];
    __shared__ int bD[NBMAX], bS[NBMAX];
    int t = threadIdx.x;
    int e0 = blockIdx.x * SCH;
    int e1 = min(e0 + SCH, E);
    if (t < NBMAX) { lhd[t] = 0; lhs[t] = 0; }
    __syncthreads();
    for (int e = e0 + t; e < e1; e += 1024) {
        uint32_t k = keys[e];
        atomicAdd(&lhd[(k >> 8) & 0xff], 1);
        atomicAdd(&lhs[k >> 24], 1);
    }
    __syncthreads();
    if (t < NB) {
        bD[t] = lhd[t] ? atomicAdd(&cd[t], lhd[t]) : 0;
        bS[t] = lhs[t] ? atomicAdd(&cs[t], lhs[t]) : 0;
        lhd[t] = 0; lhs[t] = 0;
    }
    __syncthreads();
    for (int e = e0 + t; e < e1; e += 1024) {
        uint32_t k = keys[e];
        int db = (k >> 8) & 0xff;
        int sb = k >> 24;
        int rd = atomicAdd(&lhd[db], 1);
        bd[bD[db] + rd] = k;
        int rs = atomicAdd(&lhs[sb], 1);
        __half hw = __float2half(ew[e]);
        bs[bS[sb] + rs] = ((uint32_t)*(uint16_t*)&hw << 16) | ((k >> 16) & 0xffu);
    }
}

// ---------------- Kernel C: consume bins -> ninfo -----------------
__launch_bounds__(1024)
__global__ void k_consume(const uint32_t* __restrict__ bd, const uint32_t* __restrict__ bs,
                          const int* __restrict__ offd, const int* __restrict__ offs,
                          const float* __restrict__ x, float* __restrict__ ninfo, int N) {
    __shared__ float accx[PR][6];   // xs0..xs4, cnt
    __shared__ float accd[PR];      // deg
    int t = threadIdx.x;
    int b = blockIdx.x;
    int base = b * PR;
    uint32_t pr = (uint32_t)min(PR, N - base);

    for (int k = t; k < PR * 6; k += 1024) (&accx[0][0])[k] = 0.f;
    for (int k = t; k < PR; k += 1024) accd[k] = 0.f;
    __syncthreads();

    int r0 = offd[b], r1 = offd[b + 1];
    for (int r = r0 + t; r < r1; r += 1024) {
        uint32_t k = bd[r];
        uint32_t src = k >> 16;
        uint32_t dl = k & 0xffu;
        const float* xp = x + (size_t)src * 5;
        atomicAdd(&accx[dl][0], xp[0]);
        atomicAdd(&accx[dl][1], xp[1]);
        atomicAdd(&accx[dl][2], xp[2]);
        atomicAdd(&accx[dl][3], xp[3]);
        atomicAdd(&accx[dl][4], xp[4]);
        atomicAdd(&accx[dl][5], 1.0f);
    }
    int s0 = offs[b], s1 = offs[b + 1];
    for (int r = s0 + t; r < s1; r += 1024) {
        uint32_t k = bs[r];
        uint16_t hw = (uint16_t)(k >> 16);
        atomicAdd(&accd[k & 0xffu], __half2float(*(__half*)&hw));
    }
    __syncthreads();

    for (uint32_t n = t; n < pr; n += 1024) {
        float dg = accd[n];
        float dis = (dg > 0.f) ? rsqrtf(fmaxf(dg, 1e-30f)) : 0.f;
        float* o = ninfo + (size_t)(base + n) * 8;
        *(float4*)(o + 0) = make_float4(accx[n][0], accx[n][1], accx[n][2], accx[n][3]);
        *(float4*)(o + 4) = make_float4(accx[n][4], accx[n][5], dg, dis);
    }
}

// ---------------- Kernel B: fused node phase ----------------------
__launch_bounds__(1024)
__global__ void k_node(const float* __restrict__ x,
                       const float* __restrict__ ninfo,
                       const float* __restrict__ W1p, const float* __restrict__ R1p,
                       const float* __restrict__ b1p,
                       const float* __restrict__ W1e, const float* __restrict__ R1e,
                       const float* __restrict__ b1e,
                       uint32_t* __restrict__ Sh,
                       __hip_bfloat16* __restrict__ parts,
                       float* __restrict__ scal, int N) {
    __shared__ float S_t[32][256];
    __shared__ float Y_t[32][128];
    __shared__ float red[16];

    int t = threadIdx.x;
    int wv = t >> 6, l = t & 63;
    int nl = t >> 5, sub = t & 31;

    float acc[16][2];
    #pragma unroll
    for (int ci = 0; ci < 16; ci++) { acc[ci][0] = 0.f; acc[ci][1] = 0.f; }
    float ssq = 0.f;

    int ntiles = (N + 31) >> 5;
    for (int tile = blockIdx.x; tile < ntiles; tile += (int)gridDim.x) {
        int i = tile * 32 + nl;
        if (i < N) {
            const float4* ni = (const float4*)(ninfo + (size_t)i * 8);
            float4 plo = ni[0];
            float4 phi = ni[1];
            float dg = phi.z;
            float inv_dn = 1.0f / fmaxf(phi.y, 1.0f);
            float z[10];
            z[0] = plo.x * inv_dn; z[1] = plo.y * inv_dn; z[2] = plo.z * inv_dn;
            z[3] = plo.w * inv_dn; z[4] = phi.x * inv_dn;
            const float* xp = x + (size_t)i * 5;
            z[5] = xp[0]; z[6] = xp[1]; z[7] = xp[2]; z[8] = xp[3]; z[9] = xp[4];
            float m[8];
            #pragma unroll
            for (int j = 0; j < 8; j++) {
                int c = sub + 32 * j;
                float v = b1p[c];
                #pragma unroll
                for (int d = 0; d < 5; d++) v += z[d] * W1p[d * 256 + c];
                #pragma unroll
                for (int d = 0; d < 5; d++) v += z[5 + d] * R1p[d * 256 + c];
                m[j] = v;
            }
            float mx = m[0];
            #pragma unroll
            for (int j = 1; j < 8; j++) mx = fmaxf(mx, m[j]);
            #pragma unroll
            for (int o = 16; o > 0; o >>= 1) mx = fmaxf(mx, __shfl_xor(mx, o));
            float ls = 0.f;
            #pragma unroll
            for (int j = 0; j < 8; j++) { m[j] = __expf(m[j] - mx); ls += m[j]; }
            #pragma unroll
            for (int o = 16; o > 0; o >>= 1) ls += __shfl_xor(ls, o);
            float inv_l = 1.0f / ls;
            float sq = 0.f;
            #pragma unroll
            for (int j = 0; j < 8; j++) {
                float s = m[j] * inv_l;
                m[j] = s;
                S_t[nl][sub + 32 * j] = s;
                sq += s * s;
            }
            if (dg > 0.f) ssq += sq;
            uint4 sp;
            sp.x = pack_h2(m[0], m[1]);
            sp.y = pack_h2(m[2], m[3]);
            sp.z = pack_h2(m[4], m[5]);
            sp.w = pack_h2(m[6], m[7]);
            *(uint4*)&Sh[(size_t)i * 128 + sub * 4] = sp;
            #pragma unroll
            for (int j = 0; j < 4; j++) {
                int f = sub + 32 * j;
                float v = b1e[f];
                #pragma unroll
                for (int d = 0; d < 5; d++) v += z[d] * W1e[d * 128 + f];
                #pragma unroll
                for (int d = 0; d < 5; d++) v += z[5 + d] * R1e[d * 128 + f];
                Y_t[nl][f] = fmaxf(v, 0.f);
            }
        } else {
            #pragma unroll
            for (int j = 0; j < 8; j++) S_t[nl][sub + 32 * j] = 0.f;
            #pragma unroll
            for (int j = 0; j < 4; j++) Y_t[nl][sub + 32 * j] = 0.f;
        }
        __syncthreads();
        #pragma unroll 4
        for (int k = 0; k < 32; k++) {
            float4 s0 = *(const float4*)&S_t[k][wv * 16 + 0];
            float4 s1 = *(const float4*)&S_t[k][wv * 16 + 4];
            float4 s2 = *(const float4*)&S_t[k][wv * 16 + 8];
            float4 s3 = *(const float4*)&S_t[k][wv * 16 + 12];
            float2 y  = *(const float2*)&Y_t[k][l * 2];
            float sv[16] = {s0.x, s0.y, s0.z, s0.w, s1.x, s1.y, s1.z, s1.w,
                            s2.x, s2.y, s2.z, s2.w, s3.x, s3.y, s3.z, s3.w};
            #pragma unroll
            for (int ci = 0; ci < 16; ci++) {
                acc[ci][0] += sv[ci] * y.x;
                acc[ci][1] += sv[ci] * y.y;
            }
        }
        __syncthreads();
    }

    __hip_bfloat16* part = parts + (size_t)blockIdx.x * 32768;
    #pragma unroll
    for (int ci = 0; ci < 16; ci++) {
        __hip_bfloat162 pr;
        pr.x = __float2bfloat16(acc[ci][0]);
        pr.y = __float2bfloat16(acc[ci][1]);
        *(__hip_bfloat162*)&part[(size_t)(wv * 16 + ci) * 128 + l * 2] = pr;
    }

    #pragma unroll
    for (int o = 32; o > 0; o >>= 1) ssq += __shfl_xor(ssq, o);
    if (l == 0) red[wv] = ssq;
    __syncthreads();
    if (t == 0) {
        float s = 0.f;
        #pragma unroll
        for (int w2 = 0; w2 < 16; w2++) s += red[w2];
        atomicAdd(&scal[0], s);
    }
}

// ---------------- Kernel B2: reduce partials ----------------------
__global__ void k_reduce(const __hip_bfloat16* __restrict__ parts,
                         float* __restrict__ pooled, int nparts) {
    int idx = blockIdx.x * blockDim.x + threadIdx.x;  // 32768 total
    float s = 0.f;
    for (int p = 0; p < nparts; p++)
        s += __bfloat162float(parts[(size_t)p * 32768 + idx]);
    pooled[idx] = s;
}

// ---------------- Kernel R: per-edge regularizer ------------------
__launch_bounds__(256)
__global__ void k_edge_reg(const uint32_t* __restrict__ keys, const float* __restrict__ ew,
                           const uint32_t* __restrict__ Sh, const float* __restrict__ ninfo,
                           float* __restrict__ scal, int E) {
    __shared__ float red[4];
    int t = threadIdx.x;
    int lane = t & 63;
    int sub = lane & 15;
    int grp = lane >> 4;
    int wv = t >> 6;
    int gw = blockIdx.x * (blockDim.x >> 6) + wv;
    int nwaves = gridDim.x * (blockDim.x >> 6);

    float acc = 0.f;
    for (int base = gw * 4; base < E; base += nwaves * 4) {
        int e = base + grp;
        float dot = 0.f;
        float sc = 0.f;
        if (e < E) {
            uint32_t k = keys[e];
            int s = (int)(k >> 16);
            int d = (int)(k & 0xffffu);
            const uint4* pa = (const uint4*)(Sh + (size_t)s * 128) + sub;
            const uint4* pb = (const uint4*)(Sh + (size_t)d * 128) + sub;
            uint4 A = *pa;
            uint4 B = *pb;
            dot = fdot2u(A.x, B.x, dot);
            dot = fdot2u(A.y, B.y, dot);
            dot = fdot2u(A.z, B.z, dot);
            dot = fdot2u(A.w, B.w, dot);
            sc = ew[e] * ninfo[(size_t)s * 8 + 7] * ninfo[(size_t)d * 8 + 7];
        }
        #pragma unroll
        for (int o = 8; o > 0; o >>= 1) dot += __shfl_xor(dot, o);
        if (sub == 0) acc += sc * dot;
    }

    #pragma unroll
    for (int o = 32; o > 0; o >>= 1) acc += __shfl_xor(acc, o);
    if (lane == 0) red[wv] = acc;
    __syncthreads();
    if (t == 0) atomicAdd(&scal[1], red[0] + red[1] + red[2] + red[3]);
}

// ---------------- Kernel D1: y2 column sums -----------------------
__launch_bounds__(256)
__global__ void k_pool2(const float* __restrict__ pooled,
                        const float* __restrict__ W2e, const float* __restrict__ R2e,
                        const float* __restrict__ b2e, float* __restrict__ g) {
    __shared__ float mh[128];
    __shared__ float prow[128];
    int t = threadIdx.x;
    int c = blockIdx.x;
    if (t < 128) {
        float s = 0.f;
        for (int cc = 0; cc < 256; cc++) s += pooled[cc * 128 + t];
        mh[t] = s * (1.0f / 256.0f);
        prow[t] = pooled[c * 128 + t];
    }
    __syncthreads();
    float v = b2e[t];
    for (int k = 0; k < 128; k++)
        v += mh[k] * W2e[k * 256 + t] + prow[k] * R2e[k * 256 + t];
    v = fmaxf(v, 0.f);
    atomicAdd(&g[t], v);
}

// ---------------- Kernel D2: final MLP + output -------------------
__launch_bounds__(256)
__global__ void k_final(const float* __restrict__ g,
                        const float* __restrict__ Wl1, const float* __restrict__ bl1,
                        const float* __restrict__ Wl2, const float* __restrict__ bl2,
                        const float* __restrict__ scal, float* __restrict__ out, int N) {
    __shared__ float gs[256];
    __shared__ float h1[256];
    __shared__ float lg[10];
    int t = threadIdx.x;
    gs[t] = g[t];
    __syncthreads();
    float v = bl1[t];
    for (int k = 0; k < 256; k++) v += gs[k] * Wl1[k * 256 + t];
    h1[t] = fmaxf(v, 0.f);
    __syncthreads();
    if (t < 10) {
        float s = bl2[t];
        for (int k = 0; k < 256; k++) s += h1[k] * Wl2[k * 10 + t];
        lg[t] = s;
    }
    __syncthreads();
    if (t == 0) {
        float mx = lg[0];
        for (int j = 1; j < 10; j++) mx = fmaxf(mx, lg[j]);
        float ls = 0.f;
        for (int j = 0; j < 10; j++) ls += __expf(lg[j] - mx);
        float lse = mx + logf(ls);
        for (int j = 0; j < 10; j++) out[j] = lg[j] - lse;
        out[10] = (scal[0] - scal[1]) / (float)N;
    }
}

extern "C" void kernel_launch(void* const* d_in, const int* in_sizes, int n_in,
                              void* d_out, int out_size, void* d_ws, size_t ws_size,
                              hipStream_t stream) {
    const float* x   = (const float*)d_in[0];
    const int*   ei  = (const int*)d_in[1];
    const float* ew  = (const float*)d_in[2];
    const float* W1p = (const float*)d_in[3];
    const float* R1p = (const float*)d_in[4];
    const float* b1p = (const float*)d_in[5];
    const float* W1e = (const float*)d_in[6];
    const float* R1e = (const float*)d_in[7];
    const float* b1e = (const float*)d_in[8];
    // d_in[9..11] = W2p,R2p,b2p : dead (softmax over size-1 axis == 1)
    const float* W2e = (const float*)d_in[12];
    const float* R2e = (const float*)d_in[13];
    const float* b2e = (const float*)d_in[14];
    const float* Wl1 = (const float*)d_in[15];
    const float* bl1 = (const float*)d_in[16];
    const float* Wl2 = (const float*)d_in[17];
    const float* bl2 = (const float*)d_in[18];
    float* out = (float*)d_out;

    int N = in_sizes[0] / 5;
    int E = in_sizes[1] / 2;
    int NB = (N + PR - 1) / PR;

    uint32_t* ws = (uint32_t*)d_ws;
    size_t off = 0;
    float* g    = (float*)(ws + off); off += 256;
    float* scal = (float*)(ws + off); off += 2;
    int* hd = (int*)(ws + off); off += NBMAX;
    int* hs = (int*)(ws + off); off += NBMAX;
    size_t zero_words = off;                       // accumulators to clear
    int* offd = (int*)(ws + off); off += NBMAX + 1;
    int* offs = (int*)(ws + off); off += NBMAX + 1;
    int* cd   = (int*)(ws + off); off += NBMAX;
    int* cs   = (int*)(ws + off); off += NBMAX;
    off = (off + 3) & ~(size_t)3;                  // 16B align
    float* ninfo = (float*)(ws + off); off += (size_t)N * 8;
    uint32_t* keys = ws + off; off += (size_t)E;
    uint32_t* bd   = ws + off; off += (size_t)E;
    uint32_t* bs   = ws + off; off += (size_t)E;
    off = (off + 3) & ~(size_t)3;
    uint32_t* Sh = ws + off; off += (size_t)N * 128;
    float* pooled = (float*)(ws + off); off += 32768;
    size_t avail = (ws_size / 4 > off) ? (ws_size / 4 - off) : 0;
    int nparts = (int)(avail / 16384);
    if (nparts > 256) nparts = 256;
    if (nparts < 1) nparts = 1;
    __hip_bfloat16* parts = (__hip_bfloat16*)(ws + off);

    hipMemsetAsync(d_ws, 0, zero_words * 4, stream);

    k_hist<<<104, 1024, 0, stream>>>(ei, keys, hd, hs, E);
    k_prefix<<<1, 64, 0, stream>>>(hd, hs, offd, offs, cd, cs, NB);
    k_scatter<<<(E + SCH - 1) / SCH, 1024, 0, stream>>>(keys, ew, cd, cs, bd, bs, E, NB);
    k_consume<<<NB, 1024, 0, stream>>>(bd, bs, offd, offs, x, ninfo, N);
    k_node<<<nparts, 1024, 0, stream>>>(x, ninfo, W1p, R1p, b1p,
                                        W1e, R1e, b1e, Sh, parts, scal, N);
    k_reduce<<<128, 256, 0, stream>>>(parts, pooled, nparts);
    k_edge_reg<<<2048, 256, 0, stream>>>(keys, ew, Sh, ninfo, scal, E);
    k_pool2<<<256, 256, 0, stream>>>(pooled, W2e, R2e, b2e, g);
    k_final<<<1, 256, 0, stream>>>(g, Wl1, bl1, Wl2, bl2, scal, out, N);
}

// Round 6
// 397.929 us; speedup vs baseline: 1.3477x; 1.1034x over previous
//
#include <hip/hip_runtime.h>
#include <hip/hip_bf16.h>
#include <hip/hip_fp16.h>

// ---------------- workspace layout (u32 words) ----------------
// g     [256]   f32 (atomic accum, memset 0)
// scal  [2]     f32 (ssq, sasn) (atomic accum, memset 0)
// hd    [256]   int dst-bucket histogram (memset 0)
// hs    [256]   int src-bucket histogram (memset 0)
// offd  [257], offs [257], cd [256], cs [256]  (written by k_prefix)
// ninfo [N*8]   f32 {xs0..xs4, cnt, deg, dis}
// keys  [E]     u32 (src<<16 | dst)  -- requires N <= 65536 (N=50000)
// bd    [E]     u32 dst-binned keys
// bwd   [E]     f32 dst-binned edge weights
// bs    [E]     u32 src-binned {h16(ew)<<16 | src&0xff}
// Sh    [N*128] u32 = 256 halves/node (S row, permuted layout)
// pooled[32768] f32
// parts [nparts*16384] (32768 bf16 per part)

#define PR 256
#define NBMAX 256
#define SCH 2048

typedef _Float16 half2v __attribute__((ext_vector_type(2)));

__device__ inline float fdot2u(uint32_t a, uint32_t b, float c) {
#if __has_builtin(__builtin_amdgcn_fdot2)
    return __builtin_amdgcn_fdot2(__builtin_bit_cast(half2v, a),
                                  __builtin_bit_cast(half2v, b), c, false);
#else
    __half2 ha = *reinterpret_cast<__half2*>(&a);
    __half2 hb = *reinterpret_cast<__half2*>(&b);
    float2 fa = __half22float2(ha), fb = __half22float2(hb);
    return c + fa.x * fb.x + fa.y * fb.y;
#endif
}

__device__ inline uint32_t pack_h2(float a, float b) {
    __half2 h = __floats2half2_rn(a, b);
    return *reinterpret_cast<uint32_t*>(&h);
}

// ---------------- Kernel H: pack keys + global bucket histogram ---
__launch_bounds__(1024)
__global__ void k_hist(const int* __restrict__ ei, uint32_t* __restrict__ keys,
                       int* __restrict__ hd, int* __restrict__ hs, int E) {
    __shared__ int lhd[NBMAX], lhs[NBMAX];
    int t = threadIdx.x;
    if (t < NBMAX) { lhd[t] = 0; lhs[t] = 0; }
    __syncthreads();
    int idx = blockIdx.x * blockDim.x + t;
    int stride = gridDim.x * blockDim.x;
    for (int e = idx; e < E; e += stride) {
        uint32_t s = (uint32_t)ei[e];
        uint32_t d = (uint32_t)ei[E + e];
        keys[e] = (s << 16) | d;
        atomicAdd(&lhd[d >> 8], 1);
        atomicAdd(&lhs[s >> 8], 1);
    }
    __syncthreads();
    if (t < NBMAX) {
        if (lhd[t]) atomicAdd(&hd[t], lhd[t]);
        if (lhs[t]) atomicAdd(&hs[t], lhs[t]);
    }
}

// ---------------- Kernel X: parallel exclusive prefix -------------
__launch_bounds__(NBMAX)
__global__ void k_prefix(const int* __restrict__ hd, const int* __restrict__ hs,
                         int* __restrict__ offd, int* __restrict__ offs,
                         int* __restrict__ cd, int* __restrict__ cs, int NB) {
    __shared__ int sd[NBMAX], ss[NBMAX];
    int t = threadIdx.x;
    sd[t] = (t < NB) ? hd[t] : 0;
    ss[t] = (t < NB) ? hs[t] : 0;
    __syncthreads();
    #pragma unroll
    for (int o = 1; o < NBMAX; o <<= 1) {
        int vd = (t >= o) ? sd[t - o] : 0;
        int vs = (t >= o) ? ss[t - o] : 0;
        __syncthreads();
        sd[t] += vd; ss[t] += vs;
        __syncthreads();
    }
    int ed = (t == 0) ? 0 : sd[t - 1];
    int es = (t == 0) ? 0 : ss[t - 1];
    if (t < NB) { offd[t] = ed; cd[t] = ed; offs[t] = es; cs[t] = es; }
    if (t == NB - 1) { offd[NB] = sd[t]; offs[NB] = ss[t]; }
}

// ---------------- Kernel S: block counting-sort scatter -----------
__launch_bounds__(1024)
__global__ void k_scatter(const uint32_t* __restrict__ keys, const float* __restrict__ ew,
                          int* __restrict__ cd, int* __restrict__ cs,
                          uint32_t* __restrict__ bd, float* __restrict__ bwd,
                          uint32_t* __restrict__ bs, int E, int NB) {
    __shared__ int lhd[NBMAX], lhs[NBMAX];
    __shared__ int bD[NBMAX], bS[NBMAX];
    int t = threadIdx.x;
    int e0 = blockIdx.x * SCH;
    int e1 = min(e0 + SCH, E);
    if (t < NBMAX) { lhd[t] = 0; lhs[t] = 0; }
    __syncthreads();
    for (int e = e0 + t; e < e1; e += 1024) {
        uint32_t k = keys[e];
        atomicAdd(&lhd[(k >> 8) & 0xff], 1);
        atomicAdd(&lhs[k >> 24], 1);
    }
    __syncthreads();
    if (t < NB) {
        bD[t] = lhd[t] ? atomicAdd(&cd[t], lhd[t]) : 0;
        bS[t] = lhs[t] ? atomicAdd(&cs[t], lhs[t]) : 0;
        lhd[t] = 0; lhs[t] = 0;
    }
    __syncthreads();
    for (int e = e0 + t; e < e1; e += 1024) {
        uint32_t k = keys[e];
        float w = ew[e];
        int db = (k >> 8) & 0xff;
        int sb = k >> 24;
        int rd = atomicAdd(&lhd[db], 1);
        bd[bD[db] + rd] = k;
        bwd[bD[db] + rd] = w;
        int rs = atomicAdd(&lhs[sb], 1);
        __half hw = __float2half(w);
        bs[bS[sb] + rs] = ((uint32_t)*(uint16_t*)&hw << 16) | ((k >> 16) & 0xffu);
    }
}

// ---------------- Kernel C: consume bins -> ninfo -----------------
__launch_bounds__(1024)
__global__ void k_consume(const uint32_t* __restrict__ bd, const uint32_t* __restrict__ bs,
                          const int* __restrict__ offd, const int* __restrict__ offs,
                          const float* __restrict__ x, float* __restrict__ ninfo, int N) {
    __shared__ float accx[PR][6];   // xs0..xs4, cnt
    __shared__ float accd[PR];      // deg
    int t = threadIdx.x;
    int b = blockIdx.x;
    int base = b * PR;
    uint32_t pr = (uint32_t)min(PR, N - base);

    for (int k = t; k < PR * 6; k += 1024) (&accx[0][0])[k] = 0.f;
    for (int k = t; k < PR; k += 1024) accd[k] = 0.f;
    __syncthreads();

    int r0 = offd[b], r1 = offd[b + 1];
    for (int r = r0 + t; r < r1; r += 1024) {
        uint32_t k = bd[r];
        uint32_t src = k >> 16;
        uint32_t dl = k & 0xffu;
        const float* xp = x + (size_t)src * 5;
        atomicAdd(&accx[dl][0], xp[0]);
        atomicAdd(&accx[dl][1], xp[1]);
        atomicAdd(&accx[dl][2], xp[2]);
        atomicAdd(&accx[dl][3], xp[3]);
        atomicAdd(&accx[dl][4], xp[4]);
        atomicAdd(&accx[dl][5], 1.0f);
    }
    int s0 = offs[b], s1 = offs[b + 1];
    for (int r = s0 + t; r < s1; r += 1024) {
        uint32_t k = bs[r];
        uint16_t hw = (uint16_t)(k >> 16);
        atomicAdd(&accd[k & 0xffu], __half2float(*(__half*)&hw));
    }
    __syncthreads();

    for (uint32_t n = t; n < pr; n += 1024) {
        float dg = accd[n];
        float dis = (dg > 0.f) ? rsqrtf(fmaxf(dg, 1e-30f)) : 0.f;
        float* o = ninfo + (size_t)(base + n) * 8;
        *(float4*)(o + 0) = make_float4(accx[n][0], accx[n][1], accx[n][2], accx[n][3]);
        *(float4*)(o + 4) = make_float4(accx[n][4], accx[n][5], dg, dis);
    }
}

// ---------------- Kernel B: fused node phase ----------------------
// node phase: 32 threads/node (sub = t&31, cols sub+32j);
// GEMM phase: cg=t>>5 owns 8 clusters (broadcast S), fg=t&31 owns 4 features.
__launch_bounds__(1024)
__global__ void k_node(const float* __restrict__ x,
                       const float* __restrict__ ninfo,
                       const float* __restrict__ W1p, const float* __restrict__ R1p,
                       const float* __restrict__ b1p,
                       const float* __restrict__ W1e, const float* __restrict__ R1e,
                       const float* __restrict__ b1e,
                       uint32_t* __restrict__ Sh,
                       __hip_bfloat16* __restrict__ parts,
                       float* __restrict__ scal, int N) {
    __shared__ float S_t[32][256];
    __shared__ float Y_t[32][128];
    __shared__ float red[16];

    int t = threadIdx.x;
    int wv = t >> 6, l = t & 63;
    int nl = t >> 5, sub = t & 31;
    int cg = t >> 5, fg = t & 31;

    float acc[8][4];
    #pragma unroll
    for (int a = 0; a < 8; a++)
        #pragma unroll
        for (int b = 0; b < 4; b++) acc[a][b] = 0.f;
    float ssq = 0.f;

    int ntiles = (N + 31) >> 5;
    for (int tile = blockIdx.x; tile < ntiles; tile += (int)gridDim.x) {
        int i = tile * 32 + nl;
        if (i < N) {
            const float4* ni = (const float4*)(ninfo + (size_t)i * 8);
            float4 plo = ni[0];
            float4 phi = ni[1];
            float dg = phi.z;
            float inv_dn = 1.0f / fmaxf(phi.y, 1.0f);
            float z[10];
            z[0] = plo.x * inv_dn; z[1] = plo.y * inv_dn; z[2] = plo.z * inv_dn;
            z[3] = plo.w * inv_dn; z[4] = phi.x * inv_dn;
            const float* xp = x + (size_t)i * 5;
            z[5] = xp[0]; z[6] = xp[1]; z[7] = xp[2]; z[8] = xp[3]; z[9] = xp[4];
            float m[8];
            #pragma unroll
            for (int j = 0; j < 8; j++) {
                int c = sub + 32 * j;
                float v = b1p[c];
                #pragma unroll
                for (int d = 0; d < 5; d++) v += z[d] * W1p[d * 256 + c];
                #pragma unroll
                for (int d = 0; d < 5; d++) v += z[5 + d] * R1p[d * 256 + c];
                m[j] = v;
            }
            float mx = m[0];
            #pragma unroll
            for (int j = 1; j < 8; j++) mx = fmaxf(mx, m[j]);
            #pragma unroll
            for (int o = 16; o > 0; o >>= 1) mx = fmaxf(mx, __shfl_xor(mx, o));
            float ls = 0.f;
            #pragma unroll
            for (int j = 0; j < 8; j++) { m[j] = __expf(m[j] - mx); ls += m[j]; }
            #pragma unroll
            for (int o = 16; o > 0; o >>= 1) ls += __shfl_xor(ls, o);
            float inv_l = 1.0f / ls;
            float sq = 0.f;
            #pragma unroll
            for (int j = 0; j < 8; j++) {
                float s = m[j] * inv_l;
                m[j] = s;
                S_t[nl][sub + 32 * j] = s;
                sq += s * s;
            }
            if (dg > 0.f) ssq += sq;
            uint4 sp;
            sp.x = pack_h2(m[0], m[1]);
            sp.y = pack_h2(m[2], m[3]);
            sp.z = pack_h2(m[4], m[5]);
            sp.w = pack_h2(m[6], m[7]);
            *(uint4*)&Sh[(size_t)i * 128 + sub * 4] = sp;
            #pragma unroll
            for (int j = 0; j < 4; j++) {
                int f = sub + 32 * j;
                float v = b1e[f];
                #pragma unroll
                for (int d = 0; d < 5; d++) v += z[d] * W1e[d * 128 + f];
                #pragma unroll
                for (int d = 0; d < 5; d++) v += z[5 + d] * R1e[d * 128 + f];
                Y_t[nl][f] = fmaxf(v, 0.f);
            }
        } else {
            #pragma unroll
            for (int j = 0; j < 8; j++) S_t[nl][sub + 32 * j] = 0.f;
            #pragma unroll
            for (int j = 0; j < 4; j++) Y_t[nl][sub + 32 * j] = 0.f;
        }
        __syncthreads();
        // mini-GEMM: acc[a][b] += S_t[k][cg*8+a] * Y_t[k][fg*4+b]
        #pragma unroll 4
        for (int k = 0; k < 32; k++) {
            float4 s0 = *(const float4*)&S_t[k][cg * 8 + 0];
            float4 s1 = *(const float4*)&S_t[k][cg * 8 + 4];
            float4 y  = *(const float4*)&Y_t[k][fg * 4];
            float sv[8] = {s0.x, s0.y, s0.z, s0.w, s1.x, s1.y, s1.z, s1.w};
            float yv[4] = {y.x, y.y, y.z, y.w};
            #pragma unroll
            for (int a = 0; a < 8; a++)
                #pragma unroll
                for (int b = 0; b < 4; b++)
                    acc[a][b] += sv[a] * yv[b];
        }
        __syncthreads();
    }

    // coalesced bf16 partial store: part[(cg*8+a)*128 + fg*4 + b]
    __hip_bfloat16* part = parts + (size_t)blockIdx.x * 32768;
    #pragma unroll
    for (int a = 0; a < 8; a++) {
        __hip_bfloat162 h0, h1;
        h0.x = __float2bfloat16(acc[a][0]);
        h0.y = __float2bfloat16(acc[a][1]);
        h1.x = __float2bfloat16(acc[a][2]);
        h1.y = __float2bfloat16(acc[a][3]);
        uint2 pk;
        pk.x = *(uint32_t*)&h0;
        pk.y = *(uint32_t*)&h1;
        *(uint2*)&part[(size_t)(cg * 8 + a) * 128 + fg * 4] = pk;
    }

    #pragma unroll
    for (int o = 32; o > 0; o >>= 1) ssq += __shfl_xor(ssq, o);
    if (l == 0) red[wv] = ssq;
    __syncthreads();
    if (t == 0) {
        float s = 0.f;
        #pragma unroll
        for (int w2 = 0; w2 < 16; w2++) s += red[w2];
        atomicAdd(&scal[0], s);
    }
}

// ---------------- Kernel B2: reduce partials ----------------------
__global__ void k_reduce(const __hip_bfloat16* __restrict__ parts,
                         float* __restrict__ pooled, int nparts) {
    int idx = blockIdx.x * blockDim.x + threadIdx.x;  // 32768 total
    float s = 0.f;
    #pragma unroll 4
    for (int p = 0; p < nparts; p++)
        s += __bfloat162float(parts[(size_t)p * 32768 + idx]);
    pooled[idx] = s;
}

// ---------------- Kernel R: per-edge regularizer ------------------
// Uses dst-binned edges (bd/bwd) for L2 locality on the dst S-row reads.
__launch_bounds__(256)
__global__ void k_edge_reg(const uint32_t* __restrict__ bd, const float* __restrict__ bwd,
                           const uint32_t* __restrict__ Sh, const float* __restrict__ ninfo,
                           float* __restrict__ scal, int E) {
    __shared__ float red[4];
    int t = threadIdx.x;
    int lane = t & 63;
    int sub = lane & 15;
    int grp = lane >> 4;
    int wv = t >> 6;
    int gw = blockIdx.x * (blockDim.x >> 6) + wv;
    int nwaves = gridDim.x * (blockDim.x >> 6);

    float acc = 0.f;
    for (int base = gw * 4; base < E; base += nwaves * 4) {
        int e = base + grp;
        float dot = 0.f;
        float sc = 0.f;
        if (e < E) {
            uint32_t k = bd[e];
            int s = (int)(k >> 16);
            int d = (int)(k & 0xffffu);
            const uint4* pa = (const uint4*)(Sh + (size_t)s * 128) + sub;
            const uint4* pb = (const uint4*)(Sh + (size_t)d * 128) + sub;
            uint4 A = *pa;
            uint4 B = *pb;
            dot = fdot2u(A.x, B.x, dot);
            dot = fdot2u(A.y, B.y, dot);
            dot = fdot2u(A.z, B.z, dot);
            dot = fdot2u(A.w, B.w, dot);
            sc = bwd[e] * ninfo[(size_t)s * 8 + 7] * ninfo[(size_t)d * 8 + 7];
        }
        #pragma unroll
        for (int o = 8; o > 0; o >>= 1) dot += __shfl_xor(dot, o);
        if (sub == 0) acc += sc * dot;
    }

    #pragma unroll
    for (int o = 32; o > 0; o >>= 1) acc += __shfl_xor(acc, o);
    if (lane == 0) red[wv] = acc;
    __syncthreads();
    if (t == 0) atomicAdd(&scal[1], red[0] + red[1] + red[2] + red[3]);
}

// ---------------- Kernel D1: y2 column sums -----------------------
__launch_bounds__(256)
__global__ void k_pool2(const float* __restrict__ pooled,
                        const float* __restrict__ W2e, const float* __restrict__ R2e,
                        const float* __restrict__ b2e, float* __restrict__ g) {
    __shared__ float mh[128];
    __shared__ float prow[128];
    int t = threadIdx.x;
    int c = blockIdx.x;
    if (t < 128) {
        float s = 0.f;
        for (int cc = 0; cc < 256; cc++) s += pooled[cc * 128 + t];
        mh[t] = s * (1.0f / 256.0f);
        prow[t] = pooled[c * 128 + t];
    }
    __syncthreads();
    float v = b2e[t];
    for (int k = 0; k < 128; k++)
        v += mh[k] * W2e[k * 256 + t] + prow[k] * R2e[k * 256 + t];
    v = fmaxf(v, 0.f);
    atomicAdd(&g[t], v);
}

// ---------------- Kernel D2: final MLP + output -------------------
__launch_bounds__(256)
__global__ void k_final(const float* __restrict__ g,
                        const float* __restrict__ Wl1, const float* __restrict__ bl1,
                        const float* __restrict__ Wl2, const float* __restrict__ bl2,
                        const float* __restrict__ scal, float* __restrict__ out, int N) {
    __shared__ float gs[256];
    __shared__ float h1[256];
    __shared__ float lg[10];
    int t = threadIdx.x;
    gs[t] = g[t];
    __syncthreads();
    float v = bl1[t];
    for (int k = 0; k < 256; k++) v += gs[k] * Wl1[k * 256 + t];
    h1[t] = fmaxf(v, 0.f);
    __syncthreads();
    if (t < 10) {
        float s = bl2[t];
        for (int k = 0; k < 256; k++) s += h1[k] * Wl2[k * 10 + t];
        lg[t] = s;
    }
    __syncthreads();
    if (t == 0) {
        float mx = lg[0];
        for (int j = 1; j < 10; j++) mx = fmaxf(mx, lg[j]);
        float ls = 0.f;
        for (int j = 0; j < 10; j++) ls += __expf(lg[j] - mx);
        float lse = mx + logf(ls);
        for (int j = 0; j < 10; j++) out[j] = lg[j] - lse;
        out[10] = (scal[0] - scal[1]) / (float)N;
    }
}

extern "C" void kernel_launch(void* const* d_in, const int* in_sizes, int n_in,
                              void* d_out, int out_size, void* d_ws, size_t ws_size,
                              hipStream_t stream) {
    const float* x   = (const float*)d_in[0];
    const int*   ei  = (const int*)d_in[1];
    const float* ew  = (const float*)d_in[2];
    const float* W1p = (const float*)d_in[3];
    const float* R1p = (const float*)d_in[4];
    const float* b1p = (const float*)d_in[5];
    const float* W1e = (const float*)d_in[6];
    const float* R1e = (const float*)d_in[7];
    const float* b1e = (const float*)d_in[8];
    // d_in[9..11] = W2p,R2p,b2p : dead (softmax over size-1 axis == 1)
    const float* W2e = (const float*)d_in[12];
    const float* R2e = (const float*)d_in[13];
    const float* b2e = (const float*)d_in[14];
    const float* Wl1 = (const float*)d_in[15];
    const float* bl1 = (const float*)d_in[16];
    const float* Wl2 = (const float*)d_in[17];
    const float* bl2 = (const float*)d_in[18];
    float* out = (float*)d_out;

    int N = in_sizes[0] / 5;
    int E = in_sizes[1] / 2;
    int NB = (N + PR - 1) / PR;

    uint32_t* ws = (uint32_t*)d_ws;
    size_t off = 0;
    float* g    = (float*)(ws + off); off += 256;
    float* scal = (float*)(ws + off); off += 2;
    int* hd = (int*)(ws + off); off += NBMAX;
    int* hs = (int*)(ws + off); off += NBMAX;
    size_t zero_words = off;                       // accumulators to clear
    int* offd = (int*)(ws + off); off += NBMAX + 1;
    int* offs = (int*)(ws + off); off += NBMAX + 1;
    int* cd   = (int*)(ws + off); off += NBMAX;
    int* cs   = (int*)(ws + off); off += NBMAX;
    off = (off + 3) & ~(size_t)3;                  // 16B align
    float* ninfo = (float*)(ws + off); off += (size_t)N * 8;
    uint32_t* keys = ws + off; off += (size_t)E;
    uint32_t* bd   = ws + off; off += (size_t)E;
    float*    bwd  = (float*)(ws + off); off += (size_t)E;
    uint32_t* bs   = ws + off; off += (size_t)E;
    off = (off + 3) & ~(size_t)3;
    uint32_t* Sh = ws + off; off += (size_t)N * 128;
    float* pooled = (float*)(ws + off); off += 32768;
    size_t avail = (ws_size / 4 > off) ? (ws_size / 4 - off) : 0;
    int nparts = (int)(avail / 16384);
    if (nparts > 512) nparts = 512;
    if (nparts < 1) nparts = 1;
    __hip_bfloat16* parts = (__hip_bfloat16*)(ws + off);

    hipMemsetAsync(d_ws, 0, zero_words * 4, stream);

    k_hist<<<104, 1024, 0, stream>>>(ei, keys, hd, hs, E);
    k_prefix<<<1, NBMAX, 0, stream>>>(hd, hs, offd, offs, cd, cs, NB);
    k_scatter<<<(E + SCH - 1) / SCH, 1024, 0, stream>>>(keys, ew, cd, cs, bd, bwd, bs, E, NB);
    k_consume<<<NB, 1024, 0, stream>>>(bd, bs, offd, offs, x, ninfo, N);
    k_node<<<nparts, 1024, 0, stream>>>(x, ninfo, W1p, R1p, b1p,
                                        W1e, R1e, b1e, Sh, parts, scal, N);
    k_reduce<<<128, 256, 0, stream>>>(parts, pooled, nparts);
    k_edge_reg<<<2048, 256, 0, stream>>>(bd, bwd, Sh, ninfo, scal, E);
    k_pool2<<<256, 256, 0, stream>>>(pooled, W2e, R2e, b2e, g);
    k_final<<<1, 256, 0, stream>>>(g, Wl1, bl1, Wl2, bl2, scal, out, N);
}